// Round 3
// baseline (279.828 us; speedup 1.0000x reference)
//
#include <hip/hip_runtime.h>
#include <math.h>

#define STRD  256
#define NFFT  1024
#define TIME_ 262144
#define NWIN  1021   // (262144 - 1024)/256 + 1
#define BATCH 32
#define NCPLX (33456128LL)  // 32*1021*1024

// mode 0: real part only (out_size == NCPLX)
// mode 1: planar real plane then imag plane (out_size == 2*NCPLX)
__global__ __launch_bounds__(256) void StridedFourier_kernel(
    const float* __restrict__ x, float* __restrict__ out,
    long long out_floats, int mode)
{
    __shared__ float2 A[NFFT];

    const int w = blockIdx.x;   // window index
    const int b = blockIdx.y;   // batch index
    const int t = threadIdx.x;

    const float* src = x + (size_t)b * TIME_ + (size_t)w * STRD;

    // Load 1024 real samples into LDS at bit-reversed positions (imag = 0).
#pragma unroll
    for (int i = 0; i < 4; ++i) {
        int n = t + i * 256;
        int r = (int)(__brev((unsigned)n) >> 22);   // 10-bit reversal
        A[r] = make_float2(src[n], 0.0f);
    }
    __syncthreads();

    // 10 radix-2 DIT stages, 512 butterflies/stage, 2 per thread.
    // Verified by hand at N=2 and N=4 (forward, e^{-i...}, natural-order output).
    for (int s = 0; s < 10; ++s) {
        const int half = 1 << s;
#pragma unroll
        for (int i = 0; i < 2; ++i) {
            int bi  = t + i * 256;           // butterfly index in [0, 512)
            int grp = bi >> s;
            int pos = bi & (half - 1);
            int i0  = (grp << (s + 1)) + pos;
            int i1  = i0 + half;
            float ang = -3.14159265358979323846f * (float)pos / (float)half;
            float sw, cw;
            __sincosf(ang, &sw, &cw);
            float2 u = A[i0];
            float2 v = A[i1];
            float vr = v.x * cw - v.y * sw;
            float vi = v.x * sw + v.y * cw;
            A[i0] = make_float2(u.x + vr, u.y + vi);
            A[i1] = make_float2(u.x - vr, u.y - vi);
        }
        __syncthreads();
    }

    const long long cbase = ((long long)b * NWIN + (long long)w) * NFFT;

    if (mode == 0) {
        // Real part only, coalesced float stores.
#pragma unroll
        for (int i = 0; i < 4; ++i) {
            int k = t + i * 256;
            long long fi = cbase + k;
            if (fi < out_floats) out[fi] = A[k].x;
        }
    } else {
        // Planar: real plane [0, NCPLX), imag plane [NCPLX, 2*NCPLX).
#pragma unroll
        for (int i = 0; i < 4; ++i) {
            int k = t + i * 256;
            long long fr = cbase + k;
            long long fim = NCPLX + cbase + k;
            if (fr < out_floats)  out[fr]  = A[k].x;
            if (fim < out_floats) out[fim] = A[k].y;
        }
    }
}

extern "C" void kernel_launch(void* const* d_in, const int* in_sizes, int n_in,
                              void* d_out, int out_size, void* d_ws, size_t ws_size,
                              hipStream_t stream) {
    const float* x = (const float*)d_in[0];
    float* out = (float*)d_out;
    int mode = (out_size >= 2 * (long long)NCPLX) ? 1 : 0;
    dim3 grid(NWIN, BATCH);
    StridedFourier_kernel<<<grid, 256, 0, stream>>>(x, out, (long long)out_size, mode);
}

// Round 4
// 178.218 us; speedup vs baseline: 1.5701x; 1.5701x over previous
//
#include <hip/hip_runtime.h>
#include <math.h>

#define STRD  256
#define NFFT  1024
#define TIME_ 262144
#define NWIN  1021   // (262144 - 1024)/256 + 1
#define BATCH 32

// XOR swizzle: kills LDS bank conflicts on all 5 Stockham stage patterns
// (hand-checked: every read/write phase lands <=2-way, which is free on gfx950).
#define SW(i) ((i) ^ (((i) >> 5) & 7))

__device__ __forceinline__ float2 cmul(float2 a, float2 b) {
    return make_float2(a.x * b.x - a.y * b.y, a.x * b.y + a.y * b.x);
}

// In-register 4-point DFT (forward, e^{-2pi i rk/4}).
__device__ __forceinline__ void dft4(float2 v[4]) {
    float2 a = make_float2(v[0].x + v[2].x, v[0].y + v[2].y);
    float2 b = make_float2(v[0].x - v[2].x, v[0].y - v[2].y);
    float2 c = make_float2(v[1].x + v[3].x, v[1].y + v[3].y);
    float2 d = make_float2(v[1].x - v[3].x, v[1].y - v[3].y);
    v[0] = make_float2(a.x + c.x, a.y + c.y);
    v[2] = make_float2(a.x - c.x, a.y - c.y);
    v[1] = make_float2(b.x + d.y, b.y - d.x);   // b - i*d
    v[3] = make_float2(b.x - d.y, b.y + d.x);   // b + i*d
}

// Twiddle by w^r for r=1..3 where w = exp(-2pi i * m / (4*Ns)).
__device__ __forceinline__ void twiddle(float2 v[4], int m, float invNs4) {
    float ang = -6.28318530717958647692f * (float)m * invNs4;
    float s1, c1;
    __sincosf(ang, &s1, &c1);
    float2 w1 = make_float2(c1, s1);
    float2 w2 = cmul(w1, w1);
    float2 w3 = cmul(w2, w1);
    v[1] = cmul(v[1], w1);
    v[2] = cmul(v[2], w2);
    v[3] = cmul(v[3], w3);
}

// Stockham radix-4, N=1024, 256 threads, 4 complex elems/thread in registers.
// Stage Ns=1 reads global (coalesced), stages Ns=4,16,64 go through LDS
// ping-pong, stage Ns=256 writes Re to global (coalesced). Natural order in,
// natural order out — no bit reversal.
__global__ __launch_bounds__(256) void StridedFourier_kernel(
    const float* __restrict__ x, float* __restrict__ out, long long out_floats)
{
    __shared__ float2 B[2][NFFT];

    const int j = threadIdx.x;          // 0..255
    const int w = blockIdx.x;           // window
    const int b = blockIdx.y;           // batch

    const float* src = x + (size_t)b * TIME_ + (size_t)w * STRD;

    float2 v[4];

    // ---- stage 0: Ns=1 (no twiddle), global -> registers -> LDS ----
#pragma unroll
    for (int r = 0; r < 4; ++r)
        v[r] = make_float2(src[j + 256 * r], 0.0f);
    dft4(v);
#pragma unroll
    for (int r = 0; r < 4; ++r)
        B[0][SW(4 * j + r)] = v[r];
    __syncthreads();

    // ---- stages Ns = 4, 16, 64 : LDS ping-pong ----
    int cur = 0;
#pragma unroll
    for (int it = 1; it < 4; ++it) {
        const int Ns   = 1 << (2 * it);       // 4, 16, 64
        const int m    = j & (Ns - 1);
#pragma unroll
        for (int r = 0; r < 4; ++r)
            v[r] = B[cur][SW(j + 256 * r)];
        twiddle(v, m, 1.0f / (float)(4 * Ns));
        dft4(v);
        const int idxD = ((j >> (2 * it)) << (2 * it + 2)) + m;  // (j/Ns)*4Ns + m
#pragma unroll
        for (int r = 0; r < 4; ++r)
            B[1 - cur][SW(idxD + Ns * r)] = v[r];
        cur = 1 - cur;
        __syncthreads();
    }

    // ---- stage Ns=256: LDS -> registers, write real part to global ----
#pragma unroll
    for (int r = 0; r < 4; ++r)
        v[r] = B[cur][SW(j + 256 * r)];
    twiddle(v, j, 1.0f / 1024.0f);
    dft4(v);

    const long long cbase = ((long long)b * NWIN + (long long)w) * NFFT;
#pragma unroll
    for (int r = 0; r < 4; ++r) {
        long long fi = cbase + j + 256 * r;   // idxD = j, stride Ns=256
        if (fi < out_floats) out[fi] = v[r].x;
    }
}

extern "C" void kernel_launch(void* const* d_in, const int* in_sizes, int n_in,
                              void* d_out, int out_size, void* d_ws, size_t ws_size,
                              hipStream_t stream) {
    const float* x = (const float*)d_in[0];
    float* out = (float*)d_out;
    dim3 grid(NWIN, BATCH);
    StridedFourier_kernel<<<grid, 256, 0, stream>>>(x, out, (long long)out_size);
}

// Round 5
// 163.146 us; speedup vs baseline: 1.7152x; 1.0924x over previous
//
#include <hip/hip_runtime.h>
#include <math.h>

#define STRD  256
#define NFFT  1024
#define TIME_ 262144
#define NWIN  1021   // (262144 - 1024)/256 + 1
#define NPAIR 511    // ceil(1021/2): pair p covers windows 2p, 2p+1
#define BATCH 32

// XOR swizzle: <=2-way LDS aliasing (free on gfx950) on all stage patterns.
#define SW(i) ((i) ^ (((i) >> 5) & 7))

__device__ __forceinline__ float2 cmul(float2 a, float2 b) {
    return make_float2(a.x * b.x - a.y * b.y, a.x * b.y + a.y * b.x);
}

// In-register 4-point DFT (forward, e^{-2pi i rk/4}).
__device__ __forceinline__ void dft4(float2 v[4]) {
    float2 a = make_float2(v[0].x + v[2].x, v[0].y + v[2].y);
    float2 b = make_float2(v[0].x - v[2].x, v[0].y - v[2].y);
    float2 c = make_float2(v[1].x + v[3].x, v[1].y + v[3].y);
    float2 d = make_float2(v[1].x - v[3].x, v[1].y - v[3].y);
    v[0] = make_float2(a.x + c.x, a.y + c.y);
    v[2] = make_float2(a.x - c.x, a.y - c.y);
    v[1] = make_float2(b.x + d.y, b.y - d.x);   // b - i*d
    v[3] = make_float2(b.x - d.y, b.y + d.x);   // b + i*d
}

// Twiddle by w^r, r=1..3, w = exp(-2pi i * m / (4*Ns)).
__device__ __forceinline__ void twiddle(float2 v[4], int m, float invNs4) {
    float ang = -6.28318530717958647692f * (float)m * invNs4;
    float s1, c1;
    __sincosf(ang, &s1, &c1);
    float2 w1 = make_float2(c1, s1);
    float2 w2 = cmul(w1, w1);
    float2 w3 = cmul(w2, w1);
    v[1] = cmul(v[1], w1);
    v[2] = cmul(v[2], w2);
    v[3] = cmul(v[3], w3);
}

// Two windows per block via the real-FFT two-for-one trick:
// s[n] = a[n] + i*b[n] (a = window 2p, b = window 2p+1, offset 256 samples).
// S = FFT1024(s);  Re A[k] = (S[k].x + S[-k].x)/2,  Re B[k] = (S[k].y + S[-k].y)/2.
__global__ __launch_bounds__(256) void StridedFourier_kernel(
    const float* __restrict__ x, float* __restrict__ out, long long out_floats)
{
    __shared__ float2 B[2][NFFT];

    const int j = threadIdx.x;          // 0..255
    const int p = blockIdx.x;           // window pair
    const int b = blockIdx.y;           // batch

    const int wa = 2 * p;
    const bool wbv = (2 * p + 1) < NWIN;          // last pair is a singleton

    const float* src = x + (size_t)b * TIME_ + (size_t)wa * STRD;

    // Windows 2p and 2p+1 overlap by 768 samples: load 5 blocks of 256, reuse.
    float L[5];
#pragma unroll
    for (int r = 0; r < 4; ++r) L[r] = src[j + 256 * r];
    L[4] = wbv ? src[j + 1024] : 0.0f;            // OOB only when pair is singleton

    float2 v[4];

    // ---- stage 0: Ns=1 (no twiddle), registers -> LDS ----
#pragma unroll
    for (int r = 0; r < 4; ++r)
        v[r] = make_float2(L[r], L[r + 1]);       // a[n] + i*b[n]
    dft4(v);
#pragma unroll
    for (int r = 0; r < 4; ++r)
        B[0][SW(4 * j + r)] = v[r];
    __syncthreads();

    // ---- stages Ns = 4, 16, 64 : LDS ping-pong ----
    int cur = 0;
#pragma unroll
    for (int it = 1; it < 4; ++it) {
        const int Ns = 1 << (2 * it);             // 4, 16, 64
        const int m  = j & (Ns - 1);
#pragma unroll
        for (int r = 0; r < 4; ++r)
            v[r] = B[cur][SW(j + 256 * r)];
        twiddle(v, m, 1.0f / (float)(4 * Ns));
        dft4(v);
        const int idxD = ((j >> (2 * it)) << (2 * it + 2)) + m;  // (j/Ns)*4Ns + m
#pragma unroll
        for (int r = 0; r < 4; ++r)
            B[1 - cur][SW(idxD + Ns * r)] = v[r];
        cur = 1 - cur;
        __syncthreads();
    }

    // ---- stage Ns=256 : final butterflies, park full complex S in LDS ----
#pragma unroll
    for (int r = 0; r < 4; ++r)
        v[r] = B[cur][SW(j + 256 * r)];
    twiddle(v, j, 1.0f / 1024.0f);
    dft4(v);
#pragma unroll
    for (int r = 0; r < 4; ++r)
        B[1 - cur][SW(j + 256 * r)] = v[r];       // S[k], k = j + 256r
    __syncthreads();

    // ---- untangle: two windows' real spectra from one complex FFT ----
    const long long cbase_a = ((long long)b * NWIN + (long long)wa) * NFFT;
    const long long cbase_b = cbase_a + NFFT;     // window wa+1
#pragma unroll
    for (int r = 0; r < 4; ++r) {
        int k  = j + 256 * r;
        int km = (NFFT - k) & (NFFT - 1);
        float2 Sk = B[1 - cur][SW(k)];
        float2 Sm = B[1 - cur][SW(km)];
        long long fa = cbase_a + k;
        if (fa < out_floats) out[fa] = 0.5f * (Sk.x + Sm.x);
        if (wbv) {
            long long fb = cbase_b + k;
            if (fb < out_floats) out[fb] = 0.5f * (Sk.y + Sm.y);
        }
    }
}

extern "C" void kernel_launch(void* const* d_in, const int* in_sizes, int n_in,
                              void* d_out, int out_size, void* d_ws, size_t ws_size,
                              hipStream_t stream) {
    const float* x = (const float*)d_in[0];
    float* out = (float*)d_out;
    dim3 grid(NPAIR, BATCH);
    StridedFourier_kernel<<<grid, 256, 0, stream>>>(x, out, (long long)out_size);
}